// Round 7
// baseline (131.287 us; speedup 1.0000x reference)
//
#include <hip/hip_runtime.h>
#include <hip/hip_fp16.h>

#define P_DIM 1024
#define H_DIM 256
#define L_DIM 16384
#define DT 0.001f
#define TWOPI 6.283185307179586f
#define INV2PI 0.15915494309189535f
#define WSCALE 4096.0f
#define INV_WSCALE (1.0f / 4096.0f)
#define BM 128
#define BN 128
#define BK 64
#define NT 256

typedef _Float16 f16x8 __attribute__((ext_vector_type(8)));
typedef float f32x4 __attribute__((ext_vector_type(4)));

union H2U { __half2 h; unsigned u; };

__device__ __forceinline__ float2 cmulf(float2 a, float2 b) {
    return make_float2(a.x * b.x - a.y * b.y, a.x * b.y + a.y * b.x);
}

// ---------- prep: W2[h][p] = C[h,p]*scale(p)*B[p,h] * 4096, fp16 pair ----------
__global__ __launch_bounds__(256)
void prep_kernel(const float* __restrict__ Ag, const float* __restrict__ Bg,
                 const float* __restrict__ Cg, __half* __restrict__ W2) {
    __shared__ float2 Bt[64][33];   // [p][h] tile, padded
    __shared__ float2 sc[64];
    const int t  = threadIdx.x;
    const int p0 = (blockIdx.x & 15) << 6;   // 16 p-blocks of 64
    const int h0 = (blockIdx.x >> 4) << 5;   // 8 h-blocks of 32

    if (t < 64) {
        float2 a = ((const float2*)Ag)[p0 + t];
        float er = __expf(a.x * DT);
        float s, c; __sincosf(a.y * DT, &s, &c);
        float nr = er * c - 1.f, ni = er * s;
        float inv = 1.f / (a.x * a.x + a.y * a.y);
        sc[t] = make_float2((nr * a.x + ni * a.y) * inv, (ni * a.x - nr * a.y) * inv);
    }
    #pragma unroll
    for (int i = 0; i < 8; ++i) {           // B: (p,h) layout, h fastest -> coalesced
        int idx = i * 256 + t, p = idx >> 5, h = idx & 31;
        Bt[p][h] = ((const float2*)Bg)[(size_t)(p0 + p) * H_DIM + h0 + h];
    }
    __syncthreads();
    #pragma unroll
    for (int i = 0; i < 8; ++i) {           // C: (h,p) layout, p fastest -> coalesced
        int idx = i * 256 + t, h = idx >> 6, p = idx & 63;
        float2 cc = ((const float2*)Cg)[(size_t)(h0 + h) * P_DIM + p0 + p];
        float2 s2 = sc[p], b = Bt[p][h];
        float2 tv = cmulf(cc, s2);
        float wr = (tv.x * b.x - tv.y * b.y) * WSCALE;
        float wi = (tv.x * b.y + tv.y * b.x) * WSCALE;
        ((__half2*)W2)[(size_t)(h0 + h) * P_DIM + p0 + p] =
            __float22half2_rn(make_float2(wr, wi));
    }
}

// ---------- main: W-frags global->reg (L2-hot), only V through LDS ----------
__global__ __launch_bounds__(NT, 2)
void vand_mfma_kernel(const float* __restrict__ Ag,
                      const _Float16* __restrict__ W2,
                      float* __restrict__ out) {
    __shared__ __attribute__((aligned(16))) _Float16 Bs[2][BN * BK];  // 2x16KB, XOR (VALU)
    __shared__ float4 Atab[P_DIM];   // 16KB: (abar_re, abar_im, cx, cy) per p
    // total 48KB -> 2 blocks/CU (8 waves), W never touches LDS

    const int tid  = threadIdx.x;
    const int lane = tid & 63;
    const int w    = tid >> 6;
    const int wm   = w & 1, wn = w >> 1;
    const int m0   = blockIdx.y * BM;
    const int nb   = blockIdx.x * BN;
    const int lb   = blockIdx.x * (BN / 2);

    const float2* Ag2 = (const float2*)Ag;

    // ---- Atab: A_bar and anchor coeffs per p, once per block ----
    #pragma unroll
    for (int i = 0; i < 4; ++i) {
        int p = tid + i * 256;
        float2 a = Ag2[p];
        float e = __expf(a.x * DT);
        float s, c; __sincosf(a.y * DT, &s, &c);
        Atab[p] = make_float4(e * c, e * s, a.x * DT, a.y * (DT * INV2PI));
    }

    f32x4 acc[4][4];
    #pragma unroll
    for (int mt = 0; mt < 4; ++mt)
        #pragma unroll
        for (int nt = 0; nt < 4; ++nt)
            acc[mt][nt] = (f32x4){0.f, 0.f, 0.f, 0.f};

    // V-gen mapping (r0-verified): 2 p's x 4 l's per thread, b64 stores
    const int q    = tid & 15;
    const int llq  = (tid >> 4) << 2;
    const float l0f = (float)(lb + llq);
    const int grp  = q >> 1, sub = (q & 1) << 2;

    // W fragment base: row m = m0 + wm*64 + (lane&15), k-slot (lane>>4)*8
    const _Float16* gw0 = W2 + (size_t)(m0 + wm * 64 + (lane & 15)) * 2048
                              + ((lane >> 4) << 3);

    f16x8 wA[2][4], wB[2][4];   // W frags [ks][mt], double-buffered in regs

#define WLOAD(K0, R)                                                              \
    {                                                                             \
        const _Float16* g = gw0 + (K0);                                           \
        _Pragma("unroll")                                                         \
        for (int ks = 0; ks < 2; ++ks)                                            \
            _Pragma("unroll")                                                     \
            for (int t = 0; t < 4; ++t)                                           \
                R[ks][t] = *(const f16x8*)(g + t * 32768 + ks * 32);              \
    }

#define VGEN_CHUNK(K0, DST)                                                       \
    {                                                                             \
        const int pg = ((K0) >> 1) + 2 * q;                                       \
        float4 t0 = Atab[pg], t1 = Atab[pg + 1];                                  \
        float2 ab0 = make_float2(t0.x, t0.y), ab1 = make_float2(t1.x, t1.y);      \
        float s, c;                                                               \
        float mg = __expf(t0.z * l0f);                                            \
        float x  = t0.w * l0f; x -= rintf(x); __sincosf(x * TWOPI, &s, &c);       \
        float2 v0 = make_float2(mg * c, mg * s);                                  \
        mg = __expf(t1.z * l0f);                                                  \
        x  = t1.w * l0f; x -= rintf(x); __sincosf(x * TWOPI, &s, &c);             \
        float2 v1 = make_float2(mg * c, mg * s);                                  \
        _Pragma("unroll")                                                         \
        for (int j = 0; j < 4; ++j) {                                             \
            int n0 = 2 * (llq + j);                                               \
            H2U h0u, h1u, h2u, h3u;                                               \
            h0u.h = __float22half2_rn(make_float2(v0.x, -v0.y));                  \
            h1u.h = __float22half2_rn(make_float2(v1.x, -v1.y));                  \
            h2u.h = __float22half2_rn(make_float2(v0.y, v0.x));                   \
            h3u.h = __float22half2_rn(make_float2(v1.y, v1.x));                   \
            int e0 = n0 * 64 + ((grp ^ (n0 & 7)) << 3) + sub;                     \
            int e1 = (n0 + 1) * 64 + ((grp ^ ((n0 + 1) & 7)) << 3) + sub;         \
            *(uint2*)((DST) + e0) = make_uint2(h0u.u, h1u.u);                     \
            *(uint2*)((DST) + e1) = make_uint2(h2u.u, h3u.u);                     \
            if (j < 3) { v0 = cmulf(v0, ab0); v1 = cmulf(v1, ab1); }              \
        }                                                                         \
    }

#define MFMA_PHASE(WREG, BUF)                                                     \
    {                                                                             \
        _Pragma("unroll")                                                         \
        for (int ks = 0; ks < 2; ++ks) {                                          \
            f16x8 bf[4];                                                          \
            const int g = ks * 4 + (lane >> 4);                                   \
            _Pragma("unroll")                                                     \
            for (int t = 0; t < 4; ++t) {                                         \
                int n = wn * 64 + t * 16 + (lane & 15);                           \
                bf[t] = *(const f16x8*)((BUF) + n * 64 + ((g ^ (n & 7)) << 3));   \
            }                                                                     \
            __builtin_amdgcn_s_setprio(1);                                        \
            _Pragma("unroll")                                                     \
            for (int mt = 0; mt < 4; ++mt)                                        \
                _Pragma("unroll")                                                 \
                for (int nt = 0; nt < 4; ++nt)                                    \
                    acc[mt][nt] = __builtin_amdgcn_mfma_f32_16x16x32_f16(         \
                        WREG[ks][mt], bf[nt], acc[mt][nt], 0, 0, 0);              \
            __builtin_amdgcn_s_setprio(0);                                        \
        }                                                                         \
    }

#define PUBLISH                                                                   \
    asm volatile("s_waitcnt lgkmcnt(0)" ::: "memory");                            \
    __builtin_amdgcn_sched_barrier(0);                                            \
    __builtin_amdgcn_s_barrier();                                                 \
    __builtin_amdgcn_sched_barrier(0);

#define BOTBAR                                                                    \
    __builtin_amdgcn_sched_barrier(0);                                            \
    __builtin_amdgcn_s_barrier();                                                 \
    __builtin_amdgcn_sched_barrier(0);

    // ---- prologue ----
    __syncthreads();                 // Atab visible (drains Atab-build loads)
    WLOAD(0, wA)
    VGEN_CHUNK(0, &Bs[0][0])
    PUBLISH                          // Bs[0] visible

    for (int kk = 0; kk < 32; kk += 2) {
        // ---- even half: compute chunk kk (wA, Bs[0]); prefetch kk+1 ----
        WLOAD((kk + 1) * BK, wB)
        VGEN_CHUNK((kk + 1) * BK, &Bs[1][0])
        PUBLISH                      // Bs[kk+1] published; Bs[kk] ready from prev
        MFMA_PHASE(wA, &Bs[0][0])
        BOTBAR                       // Bs[0] reads done -> safe to overwrite next
        // ---- odd half: compute chunk kk+1 (wB, Bs[1]); prefetch kk+2 ----
        {
            const int kn = (kk + 2 < 32) ? (kk + 2) : 31;
            WLOAD(kn * BK, wA)
            if (kk + 2 < 32) VGEN_CHUNK((kk + 2) * BK, &Bs[0][0])
        }
        PUBLISH
        MFMA_PHASE(wB, &Bs[1][0])
        BOTBAR
    }

    // epilogue: C/D layout col=lane&15, row=(lane>>4)*4+r
    #pragma unroll
    for (int mt = 0; mt < 4; ++mt) {
        #pragma unroll
        for (int nt = 0; nt < 4; ++nt) {
            int h = m0 + wm * 64 + mt * 16 + ((lane >> 4) << 2);
            int n = nb + wn * 64 + nt * 16 + (lane & 15);
            #pragma unroll
            for (int r = 0; r < 4; ++r)
                out[(size_t)(h + r) * 32768 + n] = acc[mt][nt][r] * INV_WSCALE;
        }
    }
#undef WLOAD
#undef VGEN_CHUNK
#undef MFMA_PHASE
#undef PUBLISH
#undef BOTBAR
}

extern "C" void kernel_launch(void* const* d_in, const int* in_sizes, int n_in,
                              void* d_out, int out_size, void* d_ws, size_t ws_size,
                              hipStream_t stream) {
    const float* A = (const float*)d_in[0];   // (P, 2)
    const float* B = (const float*)d_in[1];   // (P, H, 2)
    const float* C = (const float*)d_in[2];   // (H, P, 2)
    float* out = (float*)d_out;               // (H, L, 2)
    __half* W2 = (__half*)d_ws;               // (256, 2048) fp16, 1 MB

    prep_kernel<<<dim3(128), dim3(256), 0, stream>>>(A, B, C, W2);
    vand_mfma_kernel<<<dim3(L_DIM * 2 / BN, H_DIM / BM), dim3(NT), 0, stream>>>(
        A, (const _Float16*)W2, out);
}

// Round 8
// 115.049 us; speedup vs baseline: 1.1411x; 1.1411x over previous
//
#include <hip/hip_runtime.h>
#include <hip/hip_fp16.h>

#define P_DIM 1024
#define H_DIM 256
#define L_DIM 16384
#define DT 0.001f
#define TWOPI 6.283185307179586f
#define INV2PI 0.15915494309189535f
#define WSCALE 4096.0f
#define INV_WSCALE (1.0f / 4096.0f)
#define BM 128
#define BN 256
#define BK 64
#define NT 512

typedef _Float16 f16x8 __attribute__((ext_vector_type(8)));
typedef float f32x4 __attribute__((ext_vector_type(4)));

#define GPTR(p) (const __attribute__((address_space(1))) unsigned*)(p)
#define LPTR(p) (__attribute__((address_space(3))) unsigned*)(p)

union H2U { __half2 h; unsigned u; };

__device__ __forceinline__ float2 cmulf(float2 a, float2 b) {
    return make_float2(a.x * b.x - a.y * b.y, a.x * b.y + a.y * b.x);
}

// ---------- prep: W2[h][p] = C[h,p]*scale(p)*B[p,h] * 4096, fp16 pair ----------
__global__ __launch_bounds__(256)
void prep_kernel(const float* __restrict__ Ag, const float* __restrict__ Bg,
                 const float* __restrict__ Cg, __half* __restrict__ W2) {
    __shared__ float2 Bt[64][33];   // [p][h] tile, padded
    __shared__ float2 sc[64];
    const int t  = threadIdx.x;
    const int p0 = (blockIdx.x & 15) << 6;   // 16 p-blocks of 64
    const int h0 = (blockIdx.x >> 4) << 5;   // 8 h-blocks of 32

    if (t < 64) {
        float2 a = ((const float2*)Ag)[p0 + t];
        float er = __expf(a.x * DT);
        float s, c; __sincosf(a.y * DT, &s, &c);
        float nr = er * c - 1.f, ni = er * s;
        float inv = 1.f / (a.x * a.x + a.y * a.y);
        sc[t] = make_float2((nr * a.x + ni * a.y) * inv, (ni * a.x - nr * a.y) * inv);
    }
    #pragma unroll
    for (int i = 0; i < 8; ++i) {           // B: (p,h) layout, h fastest -> coalesced
        int idx = i * 256 + t, p = idx >> 5, h = idx & 31;
        Bt[p][h] = ((const float2*)Bg)[(size_t)(p0 + p) * H_DIM + h0 + h];
    }
    __syncthreads();
    #pragma unroll
    for (int i = 0; i < 8; ++i) {           // C: (h,p) layout, p fastest -> coalesced
        int idx = i * 256 + t, h = idx >> 6, p = idx & 63;
        float2 cc = ((const float2*)Cg)[(size_t)(h0 + h) * P_DIM + p0 + p];
        float2 s2 = sc[p], b = Bt[p][h];
        float2 tv = cmulf(cc, s2);
        float wr = (tv.x * b.x - tv.y * b.y) * WSCALE;
        float wi = (tv.x * b.y + tv.y * b.x) * WSCALE;
        ((__half2*)W2)[(size_t)(h0 + h) * P_DIM + p0 + p] =
            __float22half2_rn(make_float2(wr, wi));
    }
}

// ---------- main: 4-phase-per-K-tile counted-vmcnt cadence (T3+T4+T5) ----------
__global__ __launch_bounds__(NT, 2)
void vand_mfma_kernel(const float* __restrict__ Ag,
                      const _Float16* __restrict__ W2,
                      float* __restrict__ out) {
    __shared__ __attribute__((aligned(16))) _Float16 As[2][BM * BK];  // 2x16KB, XOR (DMA)
    __shared__ __attribute__((aligned(16))) _Float16 Bs[2][BN * BK];  // 2x32KB, XOR (VALU)
    __shared__ float4 Atab[P_DIM];   // 16KB
    // total 112KB -> 1 block/CU, 8 waves = 2/SIMD

    const int tid  = threadIdx.x;
    const int lane = tid & 63;
    const int w    = tid >> 6;           // 0..7
    const int wm   = w & 1, wn = w >> 1; // 2M x 4N waves, wave tile 64x64
    const int m0   = blockIdx.y * BM;
    const int nb   = blockIdx.x * BN;
    const int lb   = blockIdx.x * (BN / 2);

    const float2* Ag2 = (const float2*)Ag;

    #pragma unroll
    for (int i = 0; i < 2; ++i) {
        int p = tid + i * 512;
        float2 a = Ag2[p];
        float e = __expf(a.x * DT);
        float s, c; __sincosf(a.y * DT, &s, &c);
        Atab[p] = make_float4(e * c, e * s, a.x * DT, a.y * (DT * INV2PI));
    }

    f32x4 acc[4][4];
    #pragma unroll
    for (int mt = 0; mt < 4; ++mt)
        #pragma unroll
        for (int nt = 0; nt < 4; ++nt)
            acc[mt][nt] = (f32x4){0.f, 0.f, 0.f, 0.f};

    // V-gen (r0-verified): 2 p's x 4 l's per thread; 1 slice (1 l) per phase
    const int q    = tid & 15;
    const int llq  = (tid >> 4) << 2;            // 0..124
    const float l0f = (float)(lb + llq);
    const int grp  = q >> 1, sub = (q & 1) << 2;
    float2 vv0, vv1, ab0, ab1;                   // carried across phases

    // DMA mapping (r5-verified, 8 waves x 16 rows)
    const int goff = (lane >> 3) * 2048 + (((lane & 7) ^ (lane >> 3)) << 3);
    const _Float16* gwbase = W2 + (size_t)(m0 + (w << 4)) * 2048;
    const int ldsoff = (w << 4) * 64;

    _Float16* Acur = &As[0][0]; _Float16* Bcur = &Bs[0][0];
    _Float16* Anxt = &As[1][0]; _Float16* Bnxt = &Bs[1][0];

    f16x8 afr[2][4];   // A-frags for current K-tile, both ks, in regs

#define DMA_CHUNK(K0, DST)                                                        \
    {                                                                             \
        const _Float16* gw = gwbase + (K0) + goff;                                \
        _Float16* lB = (DST) + ldsoff;                                            \
        _Pragma("unroll")                                                         \
        for (int r = 0; r < 2; ++r)                                               \
            __builtin_amdgcn_global_load_lds(GPTR(gw + r * 8 * 2048),             \
                                             LPTR(lB + r * 8 * 64), 16, 0, 0);    \
    }

#define VGEN_ANCHOR(K0)                                                           \
    {                                                                             \
        const int pg = ((K0) >> 1) + 2 * q;                                       \
        float4 t0 = Atab[pg], t1 = Atab[pg + 1];                                  \
        ab0 = make_float2(t0.x, t0.y); ab1 = make_float2(t1.x, t1.y);             \
        float s, c;                                                               \
        float mg = __expf(t0.z * l0f);                                            \
        float x  = t0.w * l0f; x -= rintf(x); __sincosf(x * TWOPI, &s, &c);       \
        vv0 = make_float2(mg * c, mg * s);                                        \
        mg = __expf(t1.z * l0f);                                                  \
        x  = t1.w * l0f; x -= rintf(x); __sincosf(x * TWOPI, &s, &c);             \
        vv1 = make_float2(mg * c, mg * s);                                        \
    }

#define VGEN_SLICE(J, DST)                                                        \
    {                                                                             \
        int n0 = 2 * (llq + (J));                                                 \
        H2U h0u, h1u, h2u, h3u;                                                   \
        h0u.h = __float22half2_rn(make_float2(vv0.x, -vv0.y));                    \
        h1u.h = __float22half2_rn(make_float2(vv1.x, -vv1.y));                    \
        h2u.h = __float22half2_rn(make_float2(vv0.y, vv0.x));                     \
        h3u.h = __float22half2_rn(make_float2(vv1.y, vv1.x));                     \
        int e0 = n0 * 64 + ((grp ^ (n0 & 7)) << 3) + sub;                         \
        int e1 = (n0 + 1) * 64 + ((grp ^ ((n0 + 1) & 7)) << 3) + sub;             \
        *(uint2*)((DST) + e0) = make_uint2(h0u.u, h1u.u);                         \
        *(uint2*)((DST) + e1) = make_uint2(h2u.u, h3u.u);                         \
        vv0 = cmulf(vv0, ab0); vv1 = cmulf(vv1, ab1);                             \
    }

#define RD_AF(KS)                                                                 \
    {                                                                             \
        const int g = (KS) * 4 + (lane >> 4);                                     \
        _Pragma("unroll")                                                         \
        for (int mt = 0; mt < 4; ++mt) {                                          \
            int m = wm * 64 + mt * 16 + (lane & 15);                              \
            afr[KS][mt] = *(const f16x8*)(Acur + m * 64 + ((g ^ (m & 7)) << 3));  \
        }                                                                         \
    }

#define RD_BF(KS, NH)                                                             \
    {                                                                             \
        const int g = (KS) * 4 + (lane >> 4);                                     \
        _Pragma("unroll")                                                         \
        for (int i = 0; i < 2; ++i) {                                             \
            int n = wn * 64 + (2 * (NH) + i) * 16 + (lane & 15);                  \
            bf[i] = *(const f16x8*)(Bcur + n * 64 + ((g ^ (n & 7)) << 3));        \
        }                                                                         \
    }

#define MFMA8(KS, NH)                                                             \
    __builtin_amdgcn_s_setprio(1);                                                \
    _Pragma("unroll")                                                             \
    for (int mt = 0; mt < 4; ++mt)                                                \
        _Pragma("unroll")                                                         \
        for (int i = 0; i < 2; ++i)                                               \
            acc[mt][2 * (NH) + i] = __builtin_amdgcn_mfma_f32_16x16x32_f16(       \
                afr[KS][mt], bf[i], acc[mt][2 * (NH) + i], 0, 0, 0);              \
    __builtin_amdgcn_s_setprio(0);

#define WAIT_LGKM                                                                 \
    asm volatile("s_waitcnt lgkmcnt(0)" ::: "memory");                            \
    __builtin_amdgcn_sched_barrier(0);

#define BAR                                                                       \
    __builtin_amdgcn_sched_barrier(0);                                            \
    __builtin_amdgcn_s_barrier();                                                 \
    __builtin_amdgcn_sched_barrier(0);

    // ---- prologue: As[0] (drained), Bs[0] via full VGEN, As[1] in flight ----
    DMA_CHUNK(0, &As[0][0])
    __syncthreads();                 // Atab + As[0] visible (full drain, once)
    VGEN_ANCHOR(0)
    VGEN_SLICE(0, &Bs[0][0]) VGEN_SLICE(1, &Bs[0][0])
    VGEN_SLICE(2, &Bs[0][0]) VGEN_SLICE(3, &Bs[0][0])
    DMA_CHUNK(BK, &As[1][0])         // stays in flight until tile0 ph3 vmcnt(2)
    WAIT_LGKM
    BAR                              // Bs[0] visible

    for (int t = 0; t < 32; ++t) {
        f16x8 bf[2];
        // ---- ph0: ks0/nh0 ----
        RD_AF(0)
        RD_BF(0, 0)
        if (t < 31) { VGEN_ANCHOR((t + 1) * BK) VGEN_SLICE(0, Bnxt) }
        BAR
        WAIT_LGKM
        MFMA8(0, 0)
        BAR
        // ---- ph1: ks0/nh1 ----
        RD_BF(0, 1)
        if (t < 31) { VGEN_SLICE(1, Bnxt) }
        BAR
        WAIT_LGKM
        MFMA8(0, 1)
        BAR
        // ---- ph2: ks1/nh0 ----
        RD_AF(1)
        RD_BF(1, 0)
        if (t < 31) { VGEN_SLICE(2, Bnxt) }
        BAR
        WAIT_LGKM
        MFMA8(1, 0)
        BAR
        // ---- ph3: ks1/nh1 (+ DMA issue, counted vmcnt) ----
        RD_BF(1, 1)
        if (t < 31) { VGEN_SLICE(3, Bnxt) }
        if (t < 30) {
            DMA_CHUNK((t + 2) * BK, Acur)   // As[(t+2)&1] == current (just consumed)
            asm volatile("s_waitcnt vmcnt(2)" ::: "memory");  // DMA(t+1) landed
            __builtin_amdgcn_sched_barrier(0);
        } else if (t == 30) {
            asm volatile("s_waitcnt vmcnt(0)" ::: "memory");  // DMA(31) landed
            __builtin_amdgcn_sched_barrier(0);
        }
        BAR
        WAIT_LGKM
        MFMA8(1, 1)
        BAR

        _Float16* tA = Acur; Acur = Anxt; Anxt = tA;
        _Float16* tB = Bcur; Bcur = Bnxt; Bnxt = tB;
    }

    // epilogue: C/D layout col=lane&15, row=(lane>>4)*4+r
    #pragma unroll
    for (int mt = 0; mt < 4; ++mt) {
        #pragma unroll
        for (int nt = 0; nt < 4; ++nt) {
            int h = m0 + wm * 64 + mt * 16 + ((lane >> 4) << 2);
            int n = nb + wn * 64 + nt * 16 + (lane & 15);
            #pragma unroll
            for (int r = 0; r < 4; ++r)
                out[(size_t)(h + r) * 32768 + n] = acc[mt][nt][r] * INV_WSCALE;
        }
    }
#undef DMA_CHUNK
#undef VGEN_ANCHOR
#undef VGEN_SLICE
#undef RD_AF
#undef RD_BF
#undef MFMA8
#undef WAIT_LGKM
#undef BAR
}

extern "C" void kernel_launch(void* const* d_in, const int* in_sizes, int n_in,
                              void* d_out, int out_size, void* d_ws, size_t ws_size,
                              hipStream_t stream) {
    const float* A = (const float*)d_in[0];   // (P, 2)
    const float* B = (const float*)d_in[1];   // (P, H, 2)
    const float* C = (const float*)d_in[2];   // (H, P, 2)
    float* out = (float*)d_out;               // (H, L, 2)
    __half* W2 = (__half*)d_ws;               // (256, 2048) fp16, 1 MB

    prep_kernel<<<dim3(128), dim3(256), 0, stream>>>(A, B, C, W2);
    vand_mfma_kernel<<<dim3(L_DIM * 2 / BN, H_DIM / BM), dim3(NT), 0, stream>>>(
        A, (const _Float16*)W2, out);
}